// Round 1
// baseline (162.929 us; speedup 1.0000x reference)
//
#include <hip/hip_runtime.h>
#include <hip/hip_bf16.h>

#define HWP 9216   // H*W
#define HH  96
#define WW  96
#define CC  256    // Cin == Cout
#define NB  2

typedef __attribute__((ext_vector_type(8))) short bf16x8;
typedef __attribute__((ext_vector_type(4))) float f32x4;

__device__ inline unsigned short f2bf(float f) {
  union { __hip_bfloat16 h; unsigned short u; } cvt;
  cvt.h = __float2bfloat16(f);
  return cvt.u;
}

// ---- transpose + cvt: x (B, C, HW) f32  ->  xt (B, HW, C) bf16 ----
__global__ __launch_bounds__(256) void k_cvt_x(const float* __restrict__ x,
                                               unsigned short* __restrict__ xt) {
  __shared__ float tile[32][33];
  int b  = blockIdx.z;
  int c0 = blockIdx.y * 32;
  int p0 = blockIdx.x * 32;
  int tx = threadIdx.x;   // 0..31
  int ty = threadIdx.y;   // 0..7
  const float* src = x + ((size_t)b * CC + c0) * HWP + p0;
#pragma unroll
  for (int j = 0; j < 4; ++j)
    tile[ty + j * 8][tx] = src[(size_t)(ty + j * 8) * HWP + tx];
  __syncthreads();
  unsigned short* dst = xt + ((size_t)b * HWP + p0) * CC + c0;
#pragma unroll
  for (int j = 0; j < 4; ++j)
    dst[(size_t)(ty + j * 8) * CC + tx] = f2bf(tile[tx][ty + j * 8]);
}

// ---- cvt pw_w (256,256) f32 -> bf16 (same layout: [n][k], k contiguous) ----
__global__ __launch_bounds__(256) void k_cvt_pw(const float* __restrict__ w,
                                                unsigned short* __restrict__ wb) {
  int i = (blockIdx.x * 256 + threadIdx.x) * 4;
  float4 v = *(const float4*)(w + i);
  ushort4 o;
  o.x = f2bf(v.x); o.y = f2bf(v.y); o.z = f2bf(v.z); o.w = f2bf(v.w);
  *(ushort4*)(wb + i) = o;
}

// ---- GEMM1: xp[b, m, n] = sum_k xt[b, m, k] * wb[n, k]   (bf16 MFMA, fp32 acc)
// block = 256 thr (4 waves 2x2), tile 64x64, BK=32
__global__ __launch_bounds__(256) void k_gemm1(const unsigned short* __restrict__ xt,
                                               const unsigned short* __restrict__ wb,
                                               float* __restrict__ xp) {
  __shared__ unsigned short As[64 * 40];
  __shared__ unsigned short Bs[64 * 40];
  int b  = blockIdx.z;
  int m0 = blockIdx.x * 64;
  int n0 = blockIdx.y * 64;
  int t    = threadIdx.x;
  int lane = t & 63;
  int wid  = t >> 6;
  int wm = (wid & 1) * 32;
  int wn = (wid >> 1) * 32;

  f32x4 acc[2][2] = {};

  const unsigned short* Ag = xt + ((size_t)b * HWP + m0) * CC;
  const unsigned short* Bg = wb + (size_t)n0 * CC;

  int lr = t >> 2;          // row 0..63
  int lk = (t & 3) * 8;     // k offset 0,8,16,24

  int q = lane >> 4;        // 0..3
  int r = lane & 15;

  for (int k0 = 0; k0 < CC; k0 += 32) {
    *(uint4*)&As[lr * 40 + lk] = *(const uint4*)&Ag[(size_t)lr * CC + k0 + lk];
    *(uint4*)&Bs[lr * 40 + lk] = *(const uint4*)&Bg[(size_t)lr * CC + k0 + lk];
    __syncthreads();
#pragma unroll
    for (int tm = 0; tm < 2; ++tm) {
      bf16x8 a = *(const bf16x8*)&As[(wm + tm * 16 + r) * 40 + q * 8];
#pragma unroll
      for (int tn = 0; tn < 2; ++tn) {
        bf16x8 bb = *(const bf16x8*)&Bs[(wn + tn * 16 + r) * 40 + q * 8];
        acc[tm][tn] = __builtin_amdgcn_mfma_f32_16x16x32_bf16(a, bb, acc[tm][tn], 0, 0, 0);
      }
    }
    __syncthreads();
  }
  // C/D layout: col = lane&15, row = (lane>>4)*4 + reg
#pragma unroll
  for (int tm = 0; tm < 2; ++tm)
#pragma unroll
    for (int tn = 0; tn < 2; ++tn) {
      float* o = xp + ((size_t)b * HWP + m0 + wm + tm * 16 + q * 4) * CC
                    + n0 + wn + tn * 16 + r;
#pragma unroll
      for (int rr = 0; rr < 4; ++rr)
        o[(size_t)rr * CC] = acc[tm][tn][rr];
    }
}

// ---- offsets: off[pix, o] = sum_c xp[pix, c] * off_w[o, c] + off_b[o]
// one wave per pixel, 4 waves/block
__global__ __launch_bounds__(256) void k_off(const float* __restrict__ xp,
                                             const float* __restrict__ off_w,
                                             const float* __restrict__ off_b,
                                             float* __restrict__ offs) {
  int pix  = blockIdx.x * 4 + (threadIdx.x >> 6);
  int lane = threadIdx.x & 63;
  const float4 v = *(const float4*)(xp + (size_t)pix * CC + lane * 4);
  float part[18];
#pragma unroll
  for (int o = 0; o < 18; ++o) {
    float4 wv = *(const float4*)(off_w + o * CC + lane * 4);
    part[o] = v.x * wv.x + v.y * wv.y + v.z * wv.z + v.w * wv.w;
  }
#pragma unroll
  for (int s = 32; s > 0; s >>= 1) {
#pragma unroll
    for (int o = 0; o < 18; ++o)
      part[o] += __shfl_down(part[o], s, 64);
  }
  if (lane == 0) {
#pragma unroll
    for (int o = 0; o < 18; ++o)
      offs[(size_t)pix * 18 + o] = part[o] + off_b[o];
  }
}

// ---- gather + depthwise: one wave per output pixel, lane holds 4 channels
__global__ __launch_bounds__(256) void k_gather(const float* __restrict__ xp,
                                                const float* __restrict__ offs,
                                                const float* __restrict__ dw,
                                                float* __restrict__ out) {
  int pix  = blockIdx.x * 4 + (threadIdx.x >> 6);
  int lane = threadIdx.x & 63;
  int b  = pix / HWP;
  int hw = pix - b * HWP;
  int h  = hw / WW;
  int w  = hw - h * WW;
  int c0 = lane * 4;

  float dwr[4][9];
#pragma unroll
  for (int i = 0; i < 4; ++i)
#pragma unroll
    for (int kk = 0; kk < 9; ++kk)
      dwr[i][kk] = dw[(c0 + i) * 9 + kk];

  float offr[18];
  const float* op = offs + (size_t)pix * 18;
#pragma unroll
  for (int o = 0; o < 18; ++o) offr[o] = op[o];

  const float* xb = xp + (size_t)b * HWP * CC;
  float acc0 = 0.f, acc1 = 0.f, acc2 = 0.f, acc3 = 0.f;

#pragma unroll
  for (int kk = 0; kk < 9; ++kk) {
    float y = (float)(h - 1 + kk / 3) + offr[2 * kk];
    float x = (float)(w - 1 + kk % 3) + offr[2 * kk + 1];
    float y0f = floorf(y), x0f = floorf(x);
    float fy = y - y0f, fx = x - x0f;
    int y0 = (int)y0f, x0 = (int)x0f;
    int y1 = y0 + 1, x1 = x0 + 1;
    bool vy0 = (y0 >= 0) & (y0 < HH);
    bool vy1 = (y1 >= 0) & (y1 < HH);
    bool vx0 = (x0 >= 0) & (x0 < WW);
    bool vx1 = (x1 >= 0) & (x1 < WW);
    int y0c = y0 < 0 ? 0 : (y0 > HH - 1 ? HH - 1 : y0);
    int y1c = y1 < 0 ? 0 : (y1 > HH - 1 ? HH - 1 : y1);
    int x0c = x0 < 0 ? 0 : (x0 > WW - 1 ? WW - 1 : x0);
    int x1c = x1 < 0 ? 0 : (x1 > WW - 1 ? WW - 1 : x1);
    float w00 = (1.f - fy) * (1.f - fx) * ((vy0 && vx0) ? 1.f : 0.f);
    float w01 = (1.f - fy) * fx         * ((vy0 && vx1) ? 1.f : 0.f);
    float w10 = fy * (1.f - fx)         * ((vy1 && vx0) ? 1.f : 0.f);
    float w11 = fy * fx                 * ((vy1 && vx1) ? 1.f : 0.f);

    const float4 v00 = *(const float4*)(xb + (size_t)(y0c * WW + x0c) * CC + c0);
    const float4 v01 = *(const float4*)(xb + (size_t)(y0c * WW + x1c) * CC + c0);
    const float4 v10 = *(const float4*)(xb + (size_t)(y1c * WW + x0c) * CC + c0);
    const float4 v11 = *(const float4*)(xb + (size_t)(y1c * WW + x1c) * CC + c0);

    float s0 = w00 * v00.x + w01 * v01.x + w10 * v10.x + w11 * v11.x;
    float s1 = w00 * v00.y + w01 * v01.y + w10 * v10.y + w11 * v11.y;
    float s2 = w00 * v00.z + w01 * v01.z + w10 * v10.z + w11 * v11.z;
    float s3 = w00 * v00.w + w01 * v01.w + w10 * v10.w + w11 * v11.w;

    acc0 += dwr[0][kk] * s0;
    acc1 += dwr[1][kk] * s1;
    acc2 += dwr[2][kk] * s2;
    acc3 += dwr[3][kk] * s3;
  }

  size_t ob = (size_t)b * CC * HWP + hw;
  out[ob + (size_t)(c0 + 0) * HWP] = acc0;
  out[ob + (size_t)(c0 + 1) * HWP] = acc1;
  out[ob + (size_t)(c0 + 2) * HWP] = acc2;
  out[ob + (size_t)(c0 + 3) * HWP] = acc3;
}

extern "C" void kernel_launch(void* const* d_in, const int* in_sizes, int n_in,
                              void* d_out, int out_size, void* d_ws, size_t ws_size,
                              hipStream_t stream) {
  (void)in_sizes; (void)n_in; (void)out_size; (void)ws_size;
  const float* x     = (const float*)d_in[0];
  const float* pw_w  = (const float*)d_in[1];
  const float* off_w = (const float*)d_in[2];
  const float* off_b = (const float*)d_in[3];
  const float* dw_w  = (const float*)d_in[4];
  float* out = (float*)d_out;

  char* ws = (char*)d_ws;
  unsigned short* xt  = (unsigned short*)ws;               // B*HW*C bf16 = 9,437,184 B
  unsigned short* pwb = (unsigned short*)(ws + 9437184);   // 256*256 bf16 = 131,072 B
  float* xp   = (float*)(ws + 9568256);                    // B*HW*C f32 = 18,874,368 B
  float* offs = (float*)(ws + 28442624);                   // B*HW*18 f32 = 1,327,104 B

  k_cvt_x <<<dim3(HWP / 32, CC / 32, NB), dim3(32, 8), 0, stream>>>(x, xt);
  k_cvt_pw<<<CC * CC / (256 * 4), 256, 0, stream>>>(pw_w, pwb);
  k_gemm1 <<<dim3(HWP / 64, CC / 64, NB), 256, 0, stream>>>(xt, pwb, xp);
  k_off   <<<NB * HWP / 4, 256, 0, stream>>>(xp, off_w, off_b, offs);
  k_gather<<<NB * HWP / 4, 256, 0, stream>>>(xp, offs, dw_w, out);
}

// Round 2
// 147.551 us; speedup vs baseline: 1.1042x; 1.1042x over previous
//
#include <hip/hip_runtime.h>
#include <hip/hip_bf16.h>

#define HWP 9216   // H*W
#define HH  96
#define WW  96
#define CC  256    // Cin == Cout
#define NB  2

typedef __attribute__((ext_vector_type(8))) short bf16x8;
typedef __attribute__((ext_vector_type(4))) float f32x4;

__device__ inline unsigned short f2bf(float f) {
  union { __hip_bfloat16 h; unsigned short u; } cvt;
  cvt.h = __float2bfloat16(f);
  return cvt.u;
}
__device__ inline float bf_lo(unsigned int u) {
  return __uint_as_float(u << 16);
}
__device__ inline float bf_hi(unsigned int u) {
  return __uint_as_float(u & 0xffff0000u);
}

// ---- transpose + cvt: x (B, C, HW) f32  ->  xt (B, HW, C) bf16 ----
__global__ __launch_bounds__(256) void k_cvt_x(const float* __restrict__ x,
                                               unsigned short* __restrict__ xt) {
  __shared__ float tile[32][33];
  int b  = blockIdx.z;
  int c0 = blockIdx.y * 32;
  int p0 = blockIdx.x * 32;
  int tx = threadIdx.x;   // 0..31
  int ty = threadIdx.y;   // 0..7
  const float* src = x + ((size_t)b * CC + c0) * HWP + p0;
#pragma unroll
  for (int j = 0; j < 4; ++j)
    tile[ty + j * 8][tx] = src[(size_t)(ty + j * 8) * HWP + tx];
  __syncthreads();
  unsigned short* dst = xt + ((size_t)b * HWP + p0) * CC + c0;
#pragma unroll
  for (int j = 0; j < 4; ++j)
    dst[(size_t)(ty + j * 8) * CC + tx] = f2bf(tile[tx][ty + j * 8]);
}

// ---- cvt pw_w (256,256) f32 -> bf16 ----
__global__ __launch_bounds__(256) void k_cvt_pw(const float* __restrict__ w,
                                                unsigned short* __restrict__ wb) {
  int i = (blockIdx.x * 256 + threadIdx.x) * 4;
  float4 v = *(const float4*)(w + i);
  ushort4 o;
  o.x = f2bf(v.x); o.y = f2bf(v.y); o.z = f2bf(v.z); o.w = f2bf(v.w);
  *(ushort4*)(wb + i) = o;
}

// ---- GEMM1: xp[b, m, n] = sum_k xt[b, m, k] * wb[n, k]; output bf16 (B,HW,C)
__global__ __launch_bounds__(256) void k_gemm1(const unsigned short* __restrict__ xt,
                                               const unsigned short* __restrict__ wb,
                                               unsigned short* __restrict__ xp) {
  __shared__ unsigned short As[64 * 40];
  __shared__ unsigned short Bs[64 * 40];
  __shared__ unsigned short Cs[64 * 72];   // bf16 out tile, padded stride 72
  int b  = blockIdx.z;
  int m0 = blockIdx.x * 64;
  int n0 = blockIdx.y * 64;
  int t    = threadIdx.x;
  int lane = t & 63;
  int wid  = t >> 6;
  int wm = (wid & 1) * 32;
  int wn = (wid >> 1) * 32;

  f32x4 acc[2][2] = {};

  const unsigned short* Ag = xt + ((size_t)b * HWP + m0) * CC;
  const unsigned short* Bg = wb + (size_t)n0 * CC;

  int lr = t >> 2;          // row 0..63
  int lk = (t & 3) * 8;     // k offset 0,8,16,24

  int q = lane >> 4;        // 0..3
  int r = lane & 15;

  for (int k0 = 0; k0 < CC; k0 += 32) {
    *(uint4*)&As[lr * 40 + lk] = *(const uint4*)&Ag[(size_t)lr * CC + k0 + lk];
    *(uint4*)&Bs[lr * 40 + lk] = *(const uint4*)&Bg[(size_t)lr * CC + k0 + lk];
    __syncthreads();
#pragma unroll
    for (int tm = 0; tm < 2; ++tm) {
      bf16x8 a = *(const bf16x8*)&As[(wm + tm * 16 + r) * 40 + q * 8];
#pragma unroll
      for (int tn = 0; tn < 2; ++tn) {
        bf16x8 bb = *(const bf16x8*)&Bs[(wn + tn * 16 + r) * 40 + q * 8];
        acc[tm][tn] = __builtin_amdgcn_mfma_f32_16x16x32_bf16(a, bb, acc[tm][tn], 0, 0, 0);
      }
    }
    __syncthreads();
  }
  // C/D layout: col = lane&15, row = (lane>>4)*4 + reg → stage via LDS, emit bf16
#pragma unroll
  for (int tm = 0; tm < 2; ++tm)
#pragma unroll
    for (int tn = 0; tn < 2; ++tn)
#pragma unroll
      for (int rr = 0; rr < 4; ++rr)
        Cs[(wm + tm * 16 + q * 4 + rr) * 72 + wn + tn * 16 + r] = f2bf(acc[tm][tn][rr]);
  __syncthreads();
  // readout: thread t -> row m=t/4, col segment (t&3)*16; 32B contiguous per thread
  int m  = t >> 2;
  int cs = (t & 3) * 16;
  uint4 v0 = *(const uint4*)&Cs[m * 72 + cs];
  uint4 v1 = *(const uint4*)&Cs[m * 72 + cs + 8];
  unsigned short* o = xp + ((size_t)b * HWP + m0 + m) * CC + n0 + cs;
  *(uint4*)o = v0;
  *(uint4*)(o + 8) = v1;
}

// ---- offsets: off[pix, o] = sum_c xp[pix, c] * off_w[o, c] + off_b[o]
__global__ __launch_bounds__(256) void k_off(const unsigned short* __restrict__ xp,
                                             const float* __restrict__ off_w,
                                             const float* __restrict__ off_b,
                                             float* __restrict__ offs) {
  int pix  = blockIdx.x * 4 + (threadIdx.x >> 6);
  int lane = threadIdx.x & 63;
  uint2 u = *(const uint2*)(xp + (size_t)pix * CC + lane * 4);
  float4 v;
  v.x = bf_lo(u.x); v.y = bf_hi(u.x); v.z = bf_lo(u.y); v.w = bf_hi(u.y);
  float part[18];
#pragma unroll
  for (int o = 0; o < 18; ++o) {
    float4 wv = *(const float4*)(off_w + o * CC + lane * 4);
    part[o] = v.x * wv.x + v.y * wv.y + v.z * wv.z + v.w * wv.w;
  }
#pragma unroll
  for (int s = 32; s > 0; s >>= 1) {
#pragma unroll
    for (int o = 0; o < 18; ++o)
      part[o] += __shfl_down(part[o], s, 64);
  }
  if (lane == 0) {
#pragma unroll
    for (int o = 0; o < 18; ++o)
      offs[(size_t)pix * 20 + o] = part[o] + off_b[o];
  }
}

// ---- gather + depthwise: 16 pixels/block, XCD-swizzled; LDS-staged NCHW writes
__global__ __launch_bounds__(256) void k_gather(const unsigned short* __restrict__ xp,
                                                const float* __restrict__ offs,
                                                const float* __restrict__ dw,
                                                float* __restrict__ out) {
  __shared__ float Cs[16][257];
  // XCD swizzle: 1152 blocks -> 8 chunks of 144 contiguous-pixel blocks
  int bid = blockIdx.x;
  int sb  = (bid & 7) * 144 + (bid >> 3);
  int pix0 = sb * 16;
  int wave = threadIdx.x >> 6;
  int lane = threadIdx.x & 63;
  int c0 = lane * 4;

  float dwr[4][9];
#pragma unroll
  for (int i = 0; i < 4; ++i)
#pragma unroll
    for (int kk = 0; kk < 9; ++kk)
      dwr[i][kk] = dw[(c0 + i) * 9 + kk];

  int b   = pix0 / HWP;
  int hw0 = pix0 - b * HWP;
  const unsigned short* xb = xp + (size_t)b * HWP * CC;

#pragma unroll
  for (int p4 = 0; p4 < 4; ++p4) {
    int ip  = wave * 4 + p4;
    int hw  = hw0 + ip;
    int h   = hw / WW;
    int w   = hw - h * WW;

    const float* op = offs + (size_t)(pix0 + ip) * 20;
    float4 q0 = *(const float4*)(op + 0);
    float4 q1 = *(const float4*)(op + 4);
    float4 q2 = *(const float4*)(op + 8);
    float4 q3 = *(const float4*)(op + 12);
    float2 q4 = *(const float2*)(op + 16);
    float offr[18] = {q0.x,q0.y,q0.z,q0.w, q1.x,q1.y,q1.z,q1.w,
                      q2.x,q2.y,q2.z,q2.w, q3.x,q3.y,q3.z,q3.w, q4.x,q4.y};

    float acc0 = 0.f, acc1 = 0.f, acc2 = 0.f, acc3 = 0.f;
#pragma unroll
    for (int kk = 0; kk < 9; ++kk) {
      float y = (float)(h - 1 + kk / 3) + offr[2 * kk];
      float x = (float)(w - 1 + kk % 3) + offr[2 * kk + 1];
      float y0f = floorf(y), x0f = floorf(x);
      float fy = y - y0f, fx = x - x0f;
      int y0 = (int)y0f, x0 = (int)x0f;
      int y1 = y0 + 1, x1 = x0 + 1;
      bool vy0 = (y0 >= 0) & (y0 < HH);
      bool vy1 = (y1 >= 0) & (y1 < HH);
      bool vx0 = (x0 >= 0) & (x0 < WW);
      bool vx1 = (x1 >= 0) & (x1 < WW);
      int y0c = y0 < 0 ? 0 : (y0 > HH - 1 ? HH - 1 : y0);
      int y1c = y1 < 0 ? 0 : (y1 > HH - 1 ? HH - 1 : y1);
      int x0c = x0 < 0 ? 0 : (x0 > WW - 1 ? WW - 1 : x0);
      int x1c = x1 < 0 ? 0 : (x1 > WW - 1 ? WW - 1 : x1);
      float w00 = (1.f - fy) * (1.f - fx) * ((vy0 && vx0) ? 1.f : 0.f);
      float w01 = (1.f - fy) * fx         * ((vy0 && vx1) ? 1.f : 0.f);
      float w10 = fy * (1.f - fx)         * ((vy1 && vx0) ? 1.f : 0.f);
      float w11 = fy * fx                 * ((vy1 && vx1) ? 1.f : 0.f);

      uint2 u00 = *(const uint2*)(xb + (size_t)(y0c * WW + x0c) * CC + c0);
      uint2 u01 = *(const uint2*)(xb + (size_t)(y0c * WW + x1c) * CC + c0);
      uint2 u10 = *(const uint2*)(xb + (size_t)(y1c * WW + x0c) * CC + c0);
      uint2 u11 = *(const uint2*)(xb + (size_t)(y1c * WW + x1c) * CC + c0);

      float s0 = w00 * bf_lo(u00.x) + w01 * bf_lo(u01.x) + w10 * bf_lo(u10.x) + w11 * bf_lo(u11.x);
      float s1 = w00 * bf_hi(u00.x) + w01 * bf_hi(u01.x) + w10 * bf_hi(u10.x) + w11 * bf_hi(u11.x);
      float s2 = w00 * bf_lo(u00.y) + w01 * bf_lo(u01.y) + w10 * bf_lo(u10.y) + w11 * bf_lo(u11.y);
      float s3 = w00 * bf_hi(u00.y) + w01 * bf_hi(u01.y) + w10 * bf_hi(u10.y) + w11 * bf_hi(u11.y);

      acc0 += dwr[0][kk] * s0;
      acc1 += dwr[1][kk] * s1;
      acc2 += dwr[2][kk] * s2;
      acc3 += dwr[3][kk] * s3;
    }
    *(float4*)&Cs[ip][c0] = make_float4(acc0, acc1, acc2, acc3);
  }
  __syncthreads();
  // write-out: thread t = channel, 16 consecutive pixels = 64 B contiguous
  int ch = threadIdx.x;
  float* ob = out + (size_t)b * CC * HWP + (size_t)ch * HWP + hw0;
#pragma unroll
  for (int p4 = 0; p4 < 4; ++p4) {
    float4 v = make_float4(Cs[p4 * 4 + 0][ch], Cs[p4 * 4 + 1][ch],
                           Cs[p4 * 4 + 2][ch], Cs[p4 * 4 + 3][ch]);
    *(float4*)(ob + p4 * 4) = v;
  }
}

extern "C" void kernel_launch(void* const* d_in, const int* in_sizes, int n_in,
                              void* d_out, int out_size, void* d_ws, size_t ws_size,
                              hipStream_t stream) {
  (void)in_sizes; (void)n_in; (void)out_size; (void)ws_size;
  const float* x     = (const float*)d_in[0];
  const float* pw_w  = (const float*)d_in[1];
  const float* off_w = (const float*)d_in[2];
  const float* off_b = (const float*)d_in[3];
  const float* dw_w  = (const float*)d_in[4];
  float* out = (float*)d_out;

  char* ws = (char*)d_ws;
  unsigned short* xt  = (unsigned short*)ws;                // B*HW*C bf16 = 9,437,184 B
  unsigned short* pwb = (unsigned short*)(ws + 9437184);    // 256*256 bf16 = 131,072 B
  unsigned short* xpb = (unsigned short*)(ws + 9568256);    // B*HW*C bf16 = 9,437,184 B
  float* offs = (float*)(ws + 19005440);                    // B*HW*20 f32 = 1,474,560 B

  k_cvt_x <<<dim3(HWP / 32, CC / 32, NB), dim3(32, 8), 0, stream>>>(x, xt);
  k_cvt_pw<<<CC * CC / (256 * 4), 256, 0, stream>>>(pw_w, pwb);
  k_gemm1 <<<dim3(HWP / 64, CC / 64, NB), 256, 0, stream>>>(xt, pwb, xpb);
  k_off   <<<NB * HWP / 4, 256, 0, stream>>>(xpb, off_w, off_b, offs);
  k_gather<<<NB * HWP / 16, 256, 0, stream>>>(xpb, offs, dw_w, out);
}

// Round 4
// 147.019 us; speedup vs baseline: 1.1082x; 1.0036x over previous
//
#include <hip/hip_runtime.h>
#include <hip/hip_bf16.h>

#define HWP 9216   // H*W
#define HH  96
#define WW  96
#define CC  256    // Cin == Cout
#define NB  2

typedef __attribute__((ext_vector_type(8))) short bf16x8;
typedef __attribute__((ext_vector_type(4))) float f32x4;

__device__ inline unsigned short f2bf(float f) {
  union { __hip_bfloat16 h; unsigned short u; } cvt;
  cvt.h = __float2bfloat16(f);
  return cvt.u;
}
__device__ inline float bf_lo(unsigned int u) { return __uint_as_float(u << 16); }
__device__ inline float bf_hi(unsigned int u) { return __uint_as_float(u & 0xffff0000u); }

// ---- prep: pw_w (256x256) f32->bf16 ; off_w (18x256) f32->bf16 zero-padded to (32x256)
__global__ __launch_bounds__(256) void k_prep(const float* __restrict__ pw,
                                              const float* __restrict__ ow,
                                              unsigned short* __restrict__ pwb,
                                              unsigned short* __restrict__ wb) {
  int i = (blockIdx.x * 256 + threadIdx.x) * 4;
  if (i < CC * CC) {
    float4 v = *(const float4*)(pw + i);
    ushort4 o = make_ushort4(f2bf(v.x), f2bf(v.y), f2bf(v.z), f2bf(v.w));
    *(ushort4*)(pwb + i) = o;
  } else {
    int j = i - CC * CC;           // 0..8191
    int row = j >> 8;
    ushort4 o = make_ushort4(0, 0, 0, 0);
    if (row < 18) {
      float4 v = *(const float4*)(ow + j);
      o = make_ushort4(f2bf(v.x), f2bf(v.y), f2bf(v.z), f2bf(v.w));
    }
    *(ushort4*)(wb + j) = o;
  }
}

// ---- fused: xp = pw_w . x  (bf16 MFMA, 32 pix x 256 ch per block)
//            + offs = off_w . xp + off_b  (MFMA epilogue on the Cs tile)
__global__ __launch_bounds__(256) void k_main(const float* __restrict__ x,
                                              const unsigned short* __restrict__ pwb,
                                              const unsigned short* __restrict__ wb,
                                              const float* __restrict__ off_b,
                                              unsigned short* __restrict__ xpb,
                                              float* __restrict__ offs) {
  __shared__ unsigned short As[32 * 40];    // [pix][k]
  __shared__ unsigned short Bs[256 * 40];   // [n][k]
  __shared__ unsigned short Cs[32 * 264];   // [pix][ch] bf16, pad 264

  int b    = blockIdx.z;
  int pix0 = blockIdx.x * 32;
  int t    = threadIdx.x;
  int lane = t & 63;
  int w    = t >> 6;
  int mw = (w & 1) * 16;     // wave pixel tile
  int nw = (w >> 1) * 128;   // wave channel half
  int r = lane & 15, q = lane >> 4;

  f32x4 acc[8] = {};

  const float* xg = x + (size_t)b * CC * HWP + pix0;
  int sc = t >> 3;           // channel within 32-chunk
  int sp = (t & 7) * 4;      // pixel offset

  for (int k0 = 0; k0 < CC; k0 += 32) {
    // A: coalesced float4 (4 pixels, 1 channel) -> in-register cvt -> transposed LDS
    f32x4 xv = __builtin_nontemporal_load((const f32x4*)(xg + (size_t)(k0 + sc) * HWP + sp));
    As[(sp + 0) * 40 + sc] = f2bf(xv.x);
    As[(sp + 1) * 40 + sc] = f2bf(xv.y);
    As[(sp + 2) * 40 + sc] = f2bf(xv.z);
    As[(sp + 3) * 40 + sc] = f2bf(xv.w);
    // B: 256 rows x 32 k slice of pwb
    const unsigned short* bg = pwb + k0;
#pragma unroll
    for (int rep = 0; rep < 4; ++rep) {
      int n  = rep * 64 + (t >> 2);
      int c8 = (t & 3) * 8;
      *(uint4*)&Bs[n * 40 + c8] = *(const uint4*)(bg + n * 256 + c8);
    }
    __syncthreads();
    bf16x8 a = *(const bf16x8*)&As[(mw + r) * 40 + q * 8];
#pragma unroll
    for (int nt = 0; nt < 8; ++nt) {
      bf16x8 bb = *(const bf16x8*)&Bs[(nw + nt * 16 + r) * 40 + q * 8];
      acc[nt] = __builtin_amdgcn_mfma_f32_16x16x32_bf16(a, bb, acc[nt], 0, 0, 0);
    }
    __syncthreads();
  }

  // C/D: col = lane&15 (ch), row = q*4+rr (pix) -> Cs[pix][ch] bf16
#pragma unroll
  for (int nt = 0; nt < 8; ++nt)
#pragma unroll
    for (int rr = 0; rr < 4; ++rr)
      Cs[(mw + q * 4 + rr) * 264 + nw + nt * 16 + r] = f2bf(acc[nt][rr]);
  __syncthreads();

  // write xpb coalesced: 64 B contiguous per thread
  {
    int pix = t >> 3, c32 = (t & 7) * 32;
    unsigned short* o = xpb + ((size_t)b * HWP + pix0 + pix) * CC + c32;
#pragma unroll
    for (int j = 0; j < 4; ++j)
      *(uint4*)(o + j * 8) = *(const uint4*)&Cs[pix * 264 + c32 + j * 8];
  }

  // offset epilogue: offs[pix, o] = sum_c Cs[pix][c] * wb[o][c] + off_b[o]
  {
    int mw2 = (w & 1) * 16;    // pixel tile
    int nw2 = (w >> 1) * 16;   // o tile (0 or 16)
    f32x4 oacc = {};
#pragma unroll
    for (int ks = 0; ks < CC; ks += 32) {
      bf16x8 a = *(const bf16x8*)&Cs[(mw2 + r) * 264 + ks + q * 8];
      uint4 u = *(const uint4*)(wb + (nw2 + r) * 256 + ks + q * 8);
      bf16x8 bb;
      ((uint4*)&bb)[0] = u;
      oacc = __builtin_amdgcn_mfma_f32_16x16x32_bf16(a, bb, oacc, 0, 0, 0);
    }
    int o = nw2 + r;
    if (o < 18) {
      float ob = off_b[o];
      size_t base = ((size_t)b * HWP + pix0 + mw2 + q * 4) * 20 + o;
#pragma unroll
      for (int rr = 0; rr < 4; ++rr)
        offs[base + (size_t)rr * 20] = oacc[rr] + ob;
    }
  }
}

// ---- gather + depthwise: 16 pixels/block, XCD-swizzled; LDS-staged NCHW writes
__global__ __launch_bounds__(256) void k_gather(const unsigned short* __restrict__ xp,
                                                const float* __restrict__ offs,
                                                const float* __restrict__ dw,
                                                float* __restrict__ out) {
  __shared__ float Cs[16][257];
  int bid = blockIdx.x;
  int sb  = (bid & 7) * 144 + (bid >> 3);
  int pix0 = sb * 16;
  int wave = threadIdx.x >> 6;
  int lane = threadIdx.x & 63;
  int c0 = lane * 4;

  float dwr[4][9];
#pragma unroll
  for (int i = 0; i < 4; ++i)
#pragma unroll
    for (int kk = 0; kk < 9; ++kk)
      dwr[i][kk] = dw[(c0 + i) * 9 + kk];

  int b   = pix0 / HWP;
  int hw0 = pix0 - b * HWP;
  const unsigned short* xb = xp + (size_t)b * HWP * CC;

#pragma unroll
  for (int p4 = 0; p4 < 4; ++p4) {
    int ip  = wave * 4 + p4;
    int hw  = hw0 + ip;
    int h   = hw / WW;
    int w   = hw - h * WW;

    const float* op = offs + (size_t)(pix0 + ip) * 20;
    float4 q0 = *(const float4*)(op + 0);
    float4 q1 = *(const float4*)(op + 4);
    float4 q2 = *(const float4*)(op + 8);
    float4 q3 = *(const float4*)(op + 12);
    float2 q4 = *(const float2*)(op + 16);
    float offr[18] = {q0.x,q0.y,q0.z,q0.w, q1.x,q1.y,q1.z,q1.w,
                      q2.x,q2.y,q2.z,q2.w, q3.x,q3.y,q3.z,q3.w, q4.x,q4.y};

    float acc0 = 0.f, acc1 = 0.f, acc2 = 0.f, acc3 = 0.f;
#pragma unroll
    for (int kk = 0; kk < 9; ++kk) {
      float y = (float)(h - 1 + kk / 3) + offr[2 * kk];
      float x = (float)(w - 1 + kk % 3) + offr[2 * kk + 1];
      float y0f = floorf(y), x0f = floorf(x);
      float fy = y - y0f, fx = x - x0f;
      int y0 = (int)y0f, x0 = (int)x0f;
      int y1 = y0 + 1, x1 = x0 + 1;
      bool vy0 = (y0 >= 0) & (y0 < HH);
      bool vy1 = (y1 >= 0) & (y1 < HH);
      bool vx0 = (x0 >= 0) & (x0 < WW);
      bool vx1 = (x1 >= 0) & (x1 < WW);
      int y0c = y0 < 0 ? 0 : (y0 > HH - 1 ? HH - 1 : y0);
      int y1c = y1 < 0 ? 0 : (y1 > HH - 1 ? HH - 1 : y1);
      int x0c = x0 < 0 ? 0 : (x0 > WW - 1 ? WW - 1 : x0);
      int x1c = x1 < 0 ? 0 : (x1 > WW - 1 ? WW - 1 : x1);
      float w00 = (1.f - fy) * (1.f - fx) * ((vy0 && vx0) ? 1.f : 0.f);
      float w01 = (1.f - fy) * fx         * ((vy0 && vx1) ? 1.f : 0.f);
      float w10 = fy * (1.f - fx)         * ((vy1 && vx0) ? 1.f : 0.f);
      float w11 = fy * fx                 * ((vy1 && vx1) ? 1.f : 0.f);

      uint2 u00 = *(const uint2*)(xb + (size_t)(y0c * WW + x0c) * CC + c0);
      uint2 u01 = *(const uint2*)(xb + (size_t)(y0c * WW + x1c) * CC + c0);
      uint2 u10 = *(const uint2*)(xb + (size_t)(y1c * WW + x0c) * CC + c0);
      uint2 u11 = *(const uint2*)(xb + (size_t)(y1c * WW + x1c) * CC + c0);

      float s0 = w00 * bf_lo(u00.x) + w01 * bf_lo(u01.x) + w10 * bf_lo(u10.x) + w11 * bf_lo(u11.x);
      float s1 = w00 * bf_hi(u00.x) + w01 * bf_hi(u01.x) + w10 * bf_hi(u10.x) + w11 * bf_hi(u11.x);
      float s2 = w00 * bf_lo(u00.y) + w01 * bf_lo(u01.y) + w10 * bf_lo(u10.y) + w11 * bf_lo(u11.y);
      float s3 = w00 * bf_hi(u00.y) + w01 * bf_hi(u01.y) + w10 * bf_hi(u10.y) + w11 * bf_hi(u11.y);

      acc0 += dwr[0][kk] * s0;
      acc1 += dwr[1][kk] * s1;
      acc2 += dwr[2][kk] * s2;
      acc3 += dwr[3][kk] * s3;
    }
    *(float4*)&Cs[ip][c0] = make_float4(acc0, acc1, acc2, acc3);
  }
  __syncthreads();
  // write-out: thread t = channel, 16 consecutive pixels = 64 B contiguous (NT: write-once)
  int ch = threadIdx.x;
  float* ob = out + (size_t)b * CC * HWP + (size_t)ch * HWP + hw0;
#pragma unroll
  for (int p4 = 0; p4 < 4; ++p4) {
    f32x4 v = {Cs[p4 * 4 + 0][ch], Cs[p4 * 4 + 1][ch],
               Cs[p4 * 4 + 2][ch], Cs[p4 * 4 + 3][ch]};
    __builtin_nontemporal_store(v, (f32x4*)(ob + p4 * 4));
  }
}

extern "C" void kernel_launch(void* const* d_in, const int* in_sizes, int n_in,
                              void* d_out, int out_size, void* d_ws, size_t ws_size,
                              hipStream_t stream) {
  (void)in_sizes; (void)n_in; (void)out_size; (void)ws_size;
  const float* x     = (const float*)d_in[0];
  const float* pw_w  = (const float*)d_in[1];
  const float* off_w = (const float*)d_in[2];
  const float* off_b = (const float*)d_in[3];
  const float* dw_w  = (const float*)d_in[4];
  float* out = (float*)d_out;

  char* ws = (char*)d_ws;
  unsigned short* xpb = (unsigned short*)ws;                 // B*HW*C bf16 = 9,437,184 B
  float* offs = (float*)(ws + 9437184);                      // B*HW*20 f32 = 1,474,560 B
  unsigned short* wb  = (unsigned short*)(ws + 10911744);    // 32*256 bf16 = 16,384 B
  unsigned short* pwb = (unsigned short*)(ws + 10928128);    // 256*256 bf16 = 131,072 B

  k_prep <<<(CC * CC + 32 * CC) / 1024, 256, 0, stream>>>(pw_w, off_w, pwb, wb);
  k_main <<<dim3(HWP / 32, 1, NB), 256, 0, stream>>>(x, pwb, wb, off_b, xpb, offs);
  k_gather<<<NB * HWP / 16, 256, 0, stream>>>(xpb, offs, dw_w, out);
}

// Round 5
// 131.937 us; speedup vs baseline: 1.2349x; 1.1143x over previous
//
#include <hip/hip_runtime.h>
#include <hip/hip_bf16.h>

#define HWP 9216   // H*W
#define HH  96
#define WW  96
#define CC  256    // Cin == Cout
#define NB  2

typedef __attribute__((ext_vector_type(8))) short bf16x8;
typedef __attribute__((ext_vector_type(4))) float f32x4;

__device__ inline unsigned short f2bf(float f) {
  union { __hip_bfloat16 h; unsigned short u; } cvt;
  cvt.h = __float2bfloat16(f);
  return cvt.u;
}
__device__ inline float bf_lo(unsigned int u) { return __uint_as_float(u << 16); }
__device__ inline float bf_hi(unsigned int u) { return __uint_as_float(u & 0xffff0000u); }

// ---- prep: pw_w (256x256) f32->bf16 ; off_w (18x256) f32->bf16 zero-padded to (32x256)
__global__ __launch_bounds__(256) void k_prep(const float* __restrict__ pw,
                                              const float* __restrict__ ow,
                                              unsigned short* __restrict__ pwb,
                                              unsigned short* __restrict__ wb) {
  int i = (blockIdx.x * 256 + threadIdx.x) * 4;
  if (i < CC * CC) {
    float4 v = *(const float4*)(pw + i);
    ushort4 o = make_ushort4(f2bf(v.x), f2bf(v.y), f2bf(v.z), f2bf(v.w));
    *(ushort4*)(pwb + i) = o;
  } else {
    int j = i - CC * CC;           // 0..8191
    int row = j >> 8;
    ushort4 o = make_ushort4(0, 0, 0, 0);
    if (row < 18) {
      float4 v = *(const float4*)(ow + j);
      o = make_ushort4(f2bf(v.x), f2bf(v.y), f2bf(v.z), f2bf(v.w));
    }
    *(ushort4*)(wb + j) = o;
  }
}

// ---- fused: xp = pw_w . x  (bf16 MFMA, 32 pix x 256 ch per block)
//            + offs = off_w . xp + off_b  (MFMA epilogue on the Cs tile)
__global__ __launch_bounds__(256) void k_main(const float* __restrict__ x,
                                              const unsigned short* __restrict__ pwb,
                                              const unsigned short* __restrict__ wb,
                                              const float* __restrict__ off_b,
                                              unsigned short* __restrict__ xpb,
                                              float* __restrict__ offs) {
  __shared__ unsigned short As[32 * 40];    // [pix][k]
  __shared__ unsigned short Bs[256 * 40];   // [n][k]
  __shared__ unsigned short Cs[32 * 264];   // [pix][ch] bf16, pad 264

  int b    = blockIdx.z;
  int pix0 = blockIdx.x * 32;
  int t    = threadIdx.x;
  int lane = t & 63;
  int w    = t >> 6;
  int mw = (w & 1) * 16;     // wave pixel tile
  int nw = (w >> 1) * 128;   // wave channel half
  int r = lane & 15, q = lane >> 4;

  f32x4 acc[8] = {};

  const float* xg = x + (size_t)b * CC * HWP + pix0;
  int sc = t >> 3;           // channel within 32-chunk
  int sp = (t & 7) * 4;      // pixel offset

  for (int k0 = 0; k0 < CC; k0 += 32) {
    // A: coalesced float4 (4 pixels, 1 channel) -> in-register cvt -> transposed LDS
    f32x4 xv = __builtin_nontemporal_load((const f32x4*)(xg + (size_t)(k0 + sc) * HWP + sp));
    As[(sp + 0) * 40 + sc] = f2bf(xv.x);
    As[(sp + 1) * 40 + sc] = f2bf(xv.y);
    As[(sp + 2) * 40 + sc] = f2bf(xv.z);
    As[(sp + 3) * 40 + sc] = f2bf(xv.w);
    // B: 256 rows x 32 k slice of pwb
    const unsigned short* bg = pwb + k0;
#pragma unroll
    for (int rep = 0; rep < 4; ++rep) {
      int n  = rep * 64 + (t >> 2);
      int c8 = (t & 3) * 8;
      *(uint4*)&Bs[n * 40 + c8] = *(const uint4*)(bg + n * 256 + c8);
    }
    __syncthreads();
    bf16x8 a = *(const bf16x8*)&As[(mw + r) * 40 + q * 8];
#pragma unroll
    for (int nt = 0; nt < 8; ++nt) {
      bf16x8 bb = *(const bf16x8*)&Bs[(nw + nt * 16 + r) * 40 + q * 8];
      acc[nt] = __builtin_amdgcn_mfma_f32_16x16x32_bf16(a, bb, acc[nt], 0, 0, 0);
    }
    __syncthreads();
  }

  // C/D: col = lane&15 (ch), row = q*4+rr (pix) -> Cs[pix][ch] bf16
#pragma unroll
  for (int nt = 0; nt < 8; ++nt)
#pragma unroll
    for (int rr = 0; rr < 4; ++rr)
      Cs[(mw + q * 4 + rr) * 264 + nw + nt * 16 + r] = f2bf(acc[nt][rr]);
  __syncthreads();

  // write xpb coalesced: 64 B contiguous per thread
  {
    int pix = t >> 3, c32 = (t & 7) * 32;
    unsigned short* o = xpb + ((size_t)b * HWP + pix0 + pix) * CC + c32;
#pragma unroll
    for (int j = 0; j < 4; ++j)
      *(uint4*)(o + j * 8) = *(const uint4*)&Cs[pix * 264 + c32 + j * 8];
  }

  // offset epilogue: offs[pix, o] = sum_c Cs[pix][c] * wb[o][c] + off_b[o]
  {
    int mw2 = (w & 1) * 16;    // pixel tile
    int nw2 = (w >> 1) * 16;   // o tile (0 or 16)
    f32x4 oacc = {};
#pragma unroll
    for (int ks = 0; ks < CC; ks += 32) {
      bf16x8 a = *(const bf16x8*)&Cs[(mw2 + r) * 264 + ks + q * 8];
      uint4 u = *(const uint4*)(wb + (nw2 + r) * 256 + ks + q * 8);
      bf16x8 bb;
      ((uint4*)&bb)[0] = u;
      oacc = __builtin_amdgcn_mfma_f32_16x16x32_bf16(a, bb, oacc, 0, 0, 0);
    }
    int o = nw2 + r;
    if (o < 18) {
      float ob = off_b[o];
      size_t base = ((size_t)b * HWP + pix0 + mw2 + q * 4) * 20 + o;
#pragma unroll
      for (int rr = 0; rr < 4; ++rr)
        offs[base + (size_t)rr * 20] = oacc[rr] + ob;
    }
  }
}

// ---- gather + depthwise: 16 pixels/block, XCD-swizzled; LDS-staged NCHW writes
__global__ __launch_bounds__(256) void k_gather(const unsigned short* __restrict__ xp,
                                                const float* __restrict__ offs,
                                                const float* __restrict__ dw,
                                                float* __restrict__ out) {
  __shared__ float Cs[16][257];
  int bid = blockIdx.x;
  int sb  = (bid & 7) * 144 + (bid >> 3);
  int pix0 = sb * 16;
  int wave = threadIdx.x >> 6;
  int lane = threadIdx.x & 63;
  int c0 = lane * 4;

  float dwr[4][9];
#pragma unroll
  for (int i = 0; i < 4; ++i)
#pragma unroll
    for (int kk = 0; kk < 9; ++kk)
      dwr[i][kk] = dw[(c0 + i) * 9 + kk];

  int b   = pix0 / HWP;
  int hw0 = pix0 - b * HWP;
  const unsigned short* xb = xp + (size_t)b * HWP * CC;

#pragma unroll
  for (int p4 = 0; p4 < 4; ++p4) {
    int ip  = wave * 4 + p4;
    int hw  = hw0 + ip;
    int h   = hw / WW;
    int w   = hw - h * WW;

    const float* op = offs + (size_t)(pix0 + ip) * 20;
    float4 q0 = *(const float4*)(op + 0);
    float4 q1 = *(const float4*)(op + 4);
    float4 q2 = *(const float4*)(op + 8);
    float4 q3 = *(const float4*)(op + 12);
    float2 q4 = *(const float2*)(op + 16);
    float offr[18] = {q0.x,q0.y,q0.z,q0.w, q1.x,q1.y,q1.z,q1.w,
                      q2.x,q2.y,q2.z,q2.w, q3.x,q3.y,q3.z,q3.w, q4.x,q4.y};

    float acc0 = 0.f, acc1 = 0.f, acc2 = 0.f, acc3 = 0.f;
#pragma unroll
    for (int kk = 0; kk < 9; ++kk) {
      float y = (float)(h - 1 + kk / 3) + offr[2 * kk];
      float x = (float)(w - 1 + kk % 3) + offr[2 * kk + 1];
      float y0f = floorf(y), x0f = floorf(x);
      float fy = y - y0f, fx = x - x0f;
      int y0 = (int)y0f, x0 = (int)x0f;
      int y1 = y0 + 1, x1 = x0 + 1;
      bool vy0 = (y0 >= 0) & (y0 < HH);
      bool vy1 = (y1 >= 0) & (y1 < HH);
      bool vx0 = (x0 >= 0) & (x0 < WW);
      bool vx1 = (x1 >= 0) & (x1 < WW);
      int y0c = y0 < 0 ? 0 : (y0 > HH - 1 ? HH - 1 : y0);
      int y1c = y1 < 0 ? 0 : (y1 > HH - 1 ? HH - 1 : y1);
      int x0c = x0 < 0 ? 0 : (x0 > WW - 1 ? WW - 1 : x0);
      int x1c = x1 < 0 ? 0 : (x1 > WW - 1 ? WW - 1 : x1);
      float w00 = (1.f - fy) * (1.f - fx) * ((vy0 && vx0) ? 1.f : 0.f);
      float w01 = (1.f - fy) * fx         * ((vy0 && vx1) ? 1.f : 0.f);
      float w10 = fy * (1.f - fx)         * ((vy1 && vx0) ? 1.f : 0.f);
      float w11 = fy * fx                 * ((vy1 && vx1) ? 1.f : 0.f);

      uint2 u00 = *(const uint2*)(xb + (size_t)(y0c * WW + x0c) * CC + c0);
      uint2 u01 = *(const uint2*)(xb + (size_t)(y0c * WW + x1c) * CC + c0);
      uint2 u10 = *(const uint2*)(xb + (size_t)(y1c * WW + x0c) * CC + c0);
      uint2 u11 = *(const uint2*)(xb + (size_t)(y1c * WW + x1c) * CC + c0);

      float s0 = w00 * bf_lo(u00.x) + w01 * bf_lo(u01.x) + w10 * bf_lo(u10.x) + w11 * bf_lo(u11.x);
      float s1 = w00 * bf_hi(u00.x) + w01 * bf_hi(u01.x) + w10 * bf_hi(u10.x) + w11 * bf_hi(u11.x);
      float s2 = w00 * bf_lo(u00.y) + w01 * bf_lo(u01.y) + w10 * bf_lo(u10.y) + w11 * bf_lo(u11.y);
      float s3 = w00 * bf_hi(u00.y) + w01 * bf_hi(u01.y) + w10 * bf_hi(u10.y) + w11 * bf_hi(u11.y);

      acc0 += dwr[0][kk] * s0;
      acc1 += dwr[1][kk] * s1;
      acc2 += dwr[2][kk] * s2;
      acc3 += dwr[3][kk] * s3;
    }
    *(float4*)&Cs[ip][c0] = make_float4(acc0, acc1, acc2, acc3);
  }
  __syncthreads();
  // write-out: thread t = channel, 16 consecutive pixels = 64 B contiguous per thread.
  // NORMAL stores (not nontemporal): NT bypassed L2 write-combining and caused
  // exactly 4x WRITE_SIZE amplification (16 B partial lines) + 2x kernel time.
  int ch = threadIdx.x;
  float* ob = out + (size_t)b * CC * HWP + (size_t)ch * HWP + hw0;
#pragma unroll
  for (int p4 = 0; p4 < 4; ++p4) {
    float4 v = make_float4(Cs[p4 * 4 + 0][ch], Cs[p4 * 4 + 1][ch],
                           Cs[p4 * 4 + 2][ch], Cs[p4 * 4 + 3][ch]);
    *(float4*)(ob + p4 * 4) = v;
  }
}

extern "C" void kernel_launch(void* const* d_in, const int* in_sizes, int n_in,
                              void* d_out, int out_size, void* d_ws, size_t ws_size,
                              hipStream_t stream) {
  (void)in_sizes; (void)n_in; (void)out_size; (void)ws_size;
  const float* x     = (const float*)d_in[0];
  const float* pw_w  = (const float*)d_in[1];
  const float* off_w = (const float*)d_in[2];
  const float* off_b = (const float*)d_in[3];
  const float* dw_w  = (const float*)d_in[4];
  float* out = (float*)d_out;

  char* ws = (char*)d_ws;
  unsigned short* xpb = (unsigned short*)ws;                 // B*HW*C bf16 = 9,437,184 B
  float* offs = (float*)(ws + 9437184);                      // B*HW*20 f32 = 1,474,560 B
  unsigned short* wb  = (unsigned short*)(ws + 10911744);    // 32*256 bf16 = 16,384 B
  unsigned short* pwb = (unsigned short*)(ws + 10928128);    // 256*256 bf16 = 131,072 B

  k_prep <<<(CC * CC + 32 * CC) / 1024, 256, 0, stream>>>(pw_w, off_w, pwb, wb);
  k_main <<<dim3(HWP / 32, 1, NB), 256, 0, stream>>>(x, pwb, wb, off_b, xpb, offs);
  k_gather<<<NB * HWP / 16, 256, 0, stream>>>(xpb, offs, dw_w, out);
}